// Round 7
// baseline (155.971 us; speedup 1.0000x reference)
//
#include <hip/hip_runtime.h>
#include <hip/hip_bf16.h>

#define NROWS 2048
#define KDIM  128
#define NCELL 16
#define PORD  10
#define NJBLK 512

typedef float f32x4  __attribute__((ext_vector_type(4)));
typedef short bf16x8 __attribute__((ext_vector_type(8)));

__device__ __forceinline__ float fexp2(float x){ return __builtin_amdgcn_exp2f(x); }
__device__ __forceinline__ float flog2(float x){ return __builtin_amdgcn_logf(x); }

// sqrt(1/(2*ln2)): exp2(-((t*CS)^2)) = exp(-t^2/2)
#define CS 0.8493218002880191f

// ws float offsets
#define OFF_JOINT 0             // 2048
#define OFF_SLOGF 2048          // 2048
#define OFF_CTR   4096          // 1 uint (pad to 4100)
#define OFF_SLOGP 4100          // [64][2048] fp32
#define OFF_XS    135172        // ushort[2048*128] (65536 float slots); byte off 540688 (16B aligned)

// Hermite-series cell contribution: e^{-s^2/2} * sum_m q_m He_m(s), q_m = M_m/m!
__device__ __forceinline__ float hermS(float s,
    float q0, float q1, float q2, float q3, float q4,
    float q5, float q6, float q7, float q8, float q9){
  float scl = s * CS;
  float e = fexp2(-(scl * scl));
  float prev = 1.f, cur = s, nxt;
  float inner = fmaf(q1, s, q0);
  nxt = fmaf(s, cur, -1.f * prev); inner = fmaf(q2, nxt, inner); prev = cur; cur = nxt;
  nxt = fmaf(s, cur, -2.f * prev); inner = fmaf(q3, nxt, inner); prev = cur; cur = nxt;
  nxt = fmaf(s, cur, -3.f * prev); inner = fmaf(q4, nxt, inner); prev = cur; cur = nxt;
  nxt = fmaf(s, cur, -4.f * prev); inner = fmaf(q5, nxt, inner); prev = cur; cur = nxt;
  nxt = fmaf(s, cur, -5.f * prev); inner = fmaf(q6, nxt, inner); prev = cur; cur = nxt;
  nxt = fmaf(s, cur, -6.f * prev); inner = fmaf(q7, nxt, inner); prev = cur; cur = nxt;
  nxt = fmaf(s, cur, -7.f * prev); inner = fmaf(q8, nxt, inner); prev = cur; cur = nxt;
  nxt = fmaf(s, cur, -8.f * prev); inner = fmaf(q9, nxt, inner);
  return e * inner;
}

// ---------------- K1: stats + moments + marginal eval + bf16 pack ------------
// 64 blocks x 1024 thr; block owns columns {2b, 2b+1}; thread owns rows {t, t+1024}.
__global__ __launch_bounds__(1024) void tc_prep(const float* __restrict__ x,
                                                float* __restrict__ ws){
  const int t = threadIdx.x;
  const int b = blockIdx.x;
  const int k0 = b * 2;
  const int wave = t >> 6, lane = t & 63;

  if (b == 0){
    ws[OFF_JOINT + t] = 0.f;
    ws[OFF_JOINT + 1024 + t] = 0.f;
    if (t == 0) ((unsigned int*)(ws + OFF_CTR))[0] = 0u;
  }

  const float2 v0 = *(const float2*)(x + (size_t)t * KDIM + k0);
  const float2 v1 = *(const float2*)(x + (size_t)(t + 1024) * KDIM + k0);

  float s0 = v0.x + v1.x, s1 = v0.y + v1.y;
  float q0 = v0.x * v0.x + v1.x * v1.x, q1 = v0.y * v0.y + v1.y * v1.y;
  #pragma unroll
  for (int m = 1; m < 64; m <<= 1){
    s0 += __shfl_xor(s0, m); s1 += __shfl_xor(s1, m);
    q0 += __shfl_xor(q0, m); q1 += __shfl_xor(q1, m);
  }
  __shared__ float red[16][4];
  __shared__ float bc[4];
  __shared__ float lmP[2][2][NCELL * PORD];   // [priv][col][cell*mom]
  if (lane == 0){ red[wave][0] = s0; red[wave][1] = s1; red[wave][2] = q0; red[wave][3] = q1; }
  if (t < 640) ((float*)lmP)[t] = 0.f;
  __syncthreads();
  if (t == 0){
    float S0 = 0, S1 = 0, Q0 = 0, Q1 = 0;
    for (int w = 0; w < 16; ++w){ S0 += red[w][0]; S1 += red[w][1]; Q0 += red[w][2]; Q1 += red[w][3]; }
    float m0 = S0 * (1.f / NROWS), m1 = S1 * (1.f / NROWS);
    float var0 = fmaxf((Q0 - (float)NROWS * m0 * m0) * (1.f / (NROWS - 1)), 0.f);
    float var1 = fmaxf((Q1 - (float)NROWS * m1 * m1) * (1.f / (NROWS - 1)), 0.f);
    float c0 = 1.f / (sqrtf(var0) + 1e-6f), c1 = 1.f / (sqrtf(var1) + 1e-6f);
    bc[0] = c0; bc[1] = -m0 * c0; bc[2] = c1; bc[3] = -m1 * c1;
  }
  __syncthreads();
  const float sc0 = bc[0], sh0 = bc[1], sc1 = bc[2], sh1 = bc[3];
  const float y00 = fmaf(v0.x, sc0, sh0), y01 = fmaf(v0.y, sc1, sh1);
  const float y10 = fmaf(v1.x, sc0, sh0), y11 = fmaf(v1.y, sc1, sh1);

  // CS-folded bf16 pack (pair per row)
  {
    __hip_bfloat16 h00 = __float2bfloat16(y00 * CS), h01 = __float2bfloat16(y01 * CS);
    __hip_bfloat16 h10 = __float2bfloat16(y10 * CS), h11 = __float2bfloat16(y11 * CS);
    unsigned int p0 = ((unsigned int)*(unsigned short*)&h01 << 16) | *(unsigned short*)&h00;
    unsigned int p1 = ((unsigned int)*(unsigned short*)&h11 << 16) | *(unsigned short*)&h10;
    unsigned int* xsp = (unsigned int*)(ws + OFF_XS);
    xsp[(size_t)t * (KDIM / 2) + b] = p0;
    xsp[(size_t)(t + 1024) * (KDIM / 2) + b] = p1;
  }

  // moments (2-way wave-parity privatized LDS atomics)
  const int priv = wave & 1;
  #pragma unroll
  for (int vi = 0; vi < 4; ++vi){
    float y = (vi == 0) ? y00 : (vi == 1) ? y01 : (vi == 2) ? y10 : y11;
    int col = vi & 1;
    int c = (int)floorf(y * 2.f + 8.f);
    c = min(max(c, 0), NCELL - 1);
    float u = y - (-3.75f + 0.5f * (float)c);
    float* mm = &lmP[priv][col][c * PORD];
    atomicAdd(&mm[0], 1.f);
    float pw = u; atomicAdd(&mm[1], pw);
    pw *= u; atomicAdd(&mm[2], pw * 0.5f);
    pw *= u; atomicAdd(&mm[3], pw * 1.6666666666e-1f);
    pw *= u; atomicAdd(&mm[4], pw * 4.1666666666e-2f);
    pw *= u; atomicAdd(&mm[5], pw * 8.3333333333e-3f);
    pw *= u; atomicAdd(&mm[6], pw * 1.3888888889e-3f);
    pw *= u; atomicAdd(&mm[7], pw * 1.9841269841e-4f);
    pw *= u; atomicAdd(&mm[8], pw * 2.4801587302e-5f);
    pw *= u; atomicAdd(&mm[9], pw * 2.7557319224e-6f);
  }
  __syncthreads();
  if (t < 320) ((float*)lmP[0])[t] += ((float*)lmP[1])[t];
  __syncthreads();

  // FGT eval: 4 (row,col) pairs
  float SA0 = 0.f, SA1 = 0.f, SB0 = 0.f, SB1 = 0.f;
  #pragma unroll
  for (int c = 0; c < NCELL; ++c){
    const float ctr = -3.75f + 0.5f * (float)c;
    const float* m0 = &lmP[0][0][c * PORD];
    const float* m1 = &lmP[0][1][c * PORD];
    float a0 = m0[0], a1 = m0[1], a2 = m0[2], a3 = m0[3], a4 = m0[4];
    float a5 = m0[5], a6 = m0[6], a7 = m0[7], a8 = m0[8], a9 = m0[9];
    float b0 = m1[0], b1 = m1[1], b2 = m1[2], b3 = m1[3], b4 = m1[4];
    float b5 = m1[5], b6 = m1[6], b7 = m1[7], b8 = m1[8], b9 = m1[9];
    SA0 += hermS(y00 - ctr, a0,a1,a2,a3,a4,a5,a6,a7,a8,a9);
    SB0 += hermS(y10 - ctr, a0,a1,a2,a3,a4,a5,a6,a7,a8,a9);
    SA1 += hermS(y01 - ctr, b0,b1,b2,b3,b4,b5,b6,b7,b8,b9);
    SB1 += hermS(y11 - ctr, b0,b1,b2,b3,b4,b5,b6,b7,b8,b9);
  }
  ws[OFF_SLOGP + (size_t)b * 2048 + t]        = flog2(SA0) + flog2(SA1);
  ws[OFF_SLOGP + (size_t)b * 2048 + 1024 + t] = flog2(SB0) + flog2(SB1);
}

// ---------------- K2: MFMA Gram joint + slog reduce + finalize ---------------
// 512 blocks x 512 thr; block = (bi,bj) -> G-tile rows [bi*128,+128) x cols [bj*64,+64)
__global__ __launch_bounds__(512) void tc_joint(float* __restrict__ ws,
                                                float* __restrict__ out){
  __shared__ __align__(16) char ls[49152];      // A 32KB + B 16KB, XOR-swizzled
  __shared__ float nI[128], nJ[64];
  __shared__ float red2[8];
  __shared__ int lastflag;

  const int t = threadIdx.x;
  const int wave = t >> 6, lane = t & 63;
  const int bid = blockIdx.x;
  const int bi = bid >> 5, bj = bid & 31;
  const int Ibase = bi * 128, Jbase = bj * 64;
  float* joint = ws + OFF_JOINT;
  const unsigned short* xs = (const unsigned short*)(ws + OFF_XS);

  // side job: slog_final for rows bid*4..+3 (waves 0..3)
  if (wave < 4){
    int r = bid * 4 + wave;
    float s = ws[OFF_SLOGP + (size_t)lane * 2048 + r];
    #pragma unroll
    for (int m = 1; m < 64; m <<= 1) s += __shfl_xor(s, m);
    if (lane == 0) ws[OFF_SLOGF + r] = s;
  }

  // stage A (128 rows x 256B) and B (64 rows x 256B), swizzle byte^=(row&7)<<4
  #pragma unroll
  for (int q = 0; q < 4; ++q){
    int g = t + q * 512;                 // 0..2047 granules of 16B
    int row = g >> 4, c16 = g & 15;
    uint4 v = *(const uint4*)(xs + (size_t)(Ibase + row) * KDIM + c16 * 8);
    *(uint4*)(ls + row * 256 + ((c16 * 16) ^ ((row & 7) << 4))) = v;
  }
  #pragma unroll
  for (int q = 0; q < 2; ++q){
    int g = t + q * 512;                 // 0..1023
    int row = g >> 4, c16 = g & 15;
    uint4 v = *(const uint4*)(xs + (size_t)(Jbase + row) * KDIM + c16 * 8);
    *(uint4*)(ls + 32768 + row * 256 + ((c16 * 16) ^ ((row & 7) << 4))) = v;
  }
  __syncthreads();

  // norms from staged bf16 (consistent with MFMA inputs)
  if (t < 192){
    int row = (t < 128) ? t : (t - 128);
    const char* base = (t < 128) ? ls : (ls + 32768);
    float n = 0.f;
    #pragma unroll
    for (int g2 = 0; g2 < 16; ++g2){
      uint4 v = *(const uint4*)(base + row * 256 + ((g2 * 16) ^ ((row & 7) << 4)));
      const unsigned int* u = (const unsigned int*)&v;
      #pragma unroll
      for (int e = 0; e < 4; ++e){
        float lo = __builtin_bit_cast(float, u[e] << 16);
        float hi = __builtin_bit_cast(float, u[e] & 0xFFFF0000u);
        n = fmaf(lo, lo, n); n = fmaf(hi, hi, n);
      }
    }
    if (t < 128) nI[row] = n; else nJ[row] = n;
  }
  __syncthreads();

  // MFMA: wave (wi=wave>>2, wj=wave&3) -> 64i x 16j region, 4 m-tiles
  const int wi = wave >> 2, wj = wave & 3;
  const int mrow0 = wi * 64 + (lane & 15);
  const int nrow  = wj * 16 + (lane & 15);
  f32x4 acc0 = {0.f,0.f,0.f,0.f}, acc1 = acc0, acc2 = acc0, acc3 = acc0;
  #pragma unroll
  for (int kq = 0; kq < 4; ++kq){
    const int boff = kq * 64 + (lane >> 4) * 16;
    const int mx = (mrow0 & 7) << 4;
    bf16x8 bf = *(const bf16x8*)(ls + 32768 + nrow * 256 + (boff ^ ((nrow & 7) << 4)));
    bf16x8 a0 = *(const bf16x8*)(ls + (mrow0 +  0) * 256 + (boff ^ mx));
    bf16x8 a1 = *(const bf16x8*)(ls + (mrow0 + 16) * 256 + (boff ^ mx));
    bf16x8 a2 = *(const bf16x8*)(ls + (mrow0 + 32) * 256 + (boff ^ mx));
    bf16x8 a3 = *(const bf16x8*)(ls + (mrow0 + 48) * 256 + (boff ^ mx));
    acc0 = __builtin_amdgcn_mfma_f32_16x16x32_bf16(a0, bf, acc0, 0, 0, 0);
    acc1 = __builtin_amdgcn_mfma_f32_16x16x32_bf16(a1, bf, acc1, 0, 0, 0);
    acc2 = __builtin_amdgcn_mfma_f32_16x16x32_bf16(a2, bf, acc2, 0, 0, 0);
    acc3 = __builtin_amdgcn_mfma_f32_16x16x32_bf16(a3, bf, acc3, 0, 0, 0);
  }

  // epilogue: pd = nI + nJ - 2g; exp2(-pd) (flushes to 0 for far pairs); row-reduce
  const float njv = nJ[nrow];
  const int rbase = (lane >> 4) * 4;
  float jp[4][4];
  #pragma unroll
  for (int mt = 0; mt < 4; ++mt){
    f32x4 a4 = (mt == 0) ? acc0 : (mt == 1) ? acc1 : (mt == 2) ? acc2 : acc3;
    #pragma unroll
    for (int p = 0; p < 4; ++p){
      int iloc = wi * 64 + mt * 16 + rbase + p;
      float pd = nI[iloc] + njv - 2.f * a4[p];
      jp[mt][p] = fexp2(-pd);
    }
  }
  #pragma unroll
  for (int mt = 0; mt < 4; ++mt){
    #pragma unroll
    for (int p = 0; p < 4; ++p){
      float v = jp[mt][p];
      v += __shfl_xor(v, 1); v += __shfl_xor(v, 2);
      v += __shfl_xor(v, 4); v += __shfl_xor(v, 8);
      jp[mt][p] = v;
    }
  }
  if ((lane & 15) == 0){
    #pragma unroll
    for (int mt = 0; mt < 4; ++mt)
      #pragma unroll
      for (int p = 0; p < 4; ++p)
        atomicAdd(&joint[Ibase + wi * 64 + mt * 16 + rbase + p], jp[mt][p]);
  }

  // arrival counter; last block finalizes
  __syncthreads();
  if (t == 0){
    __threadfence();
    unsigned int* ctr = (unsigned int*)(ws + OFF_CTR);
    unsigned int old = __hip_atomic_fetch_add(ctr, 1u, __ATOMIC_ACQ_REL, __HIP_MEMORY_SCOPE_AGENT);
    lastflag = (old == NJBLK - 1);
  }
  __syncthreads();
  if (lastflag){
    float acc = 0.f;
    #pragma unroll
    for (int q = 0; q < 4; ++q){
      int r = q * 512 + t;
      float jv = __hip_atomic_load(&joint[r], __ATOMIC_RELAXED, __HIP_MEMORY_SCOPE_AGENT);
      float sv = __hip_atomic_load(ws + OFF_SLOGF + r, __ATOMIC_RELAXED, __HIP_MEMORY_SCOPE_AGENT);
      acc += 0.6931471805599453f * (flog2(jv) - sv);
    }
    #pragma unroll
    for (int m = 1; m < 64; m <<= 1) acc += __shfl_xor(acc, m);
    if (lane == 0) red2[wave] = acc;
    __syncthreads();
    if (t == 0){
      float tot = 0.f;
      #pragma unroll
      for (int w = 0; w < 8; ++w) tot += red2[w];
      out[0] = tot * (1.0f / NROWS) + 968.32661124224364f;  // +127*ln(2048)
    }
  }
}

// ---------------- launch -----------------------------------------------------
extern "C" void kernel_launch(void* const* d_in, const int* in_sizes, int n_in,
                              void* d_out, int out_size, void* d_ws, size_t ws_size,
                              hipStream_t stream){
  const float* x = (const float*)d_in[0];
  float* out = (float*)d_out;
  float* ws  = (float*)d_ws;
  tc_prep <<<64, 1024, 0, stream>>>(x, ws);
  tc_joint<<<NJBLK, 512, 0, stream>>>(ws, out);
}

// Round 8
// 124.054 us; speedup vs baseline: 1.2573x; 1.2573x over previous
//
#include <hip/hip_runtime.h>
#include <hip/hip_bf16.h>

#define NROWS 2048
#define KDIM  128
#define NCELL 16
#define PORD  10
#define NJBLK 512

typedef float f32x4  __attribute__((ext_vector_type(4)));
typedef short bf16x8 __attribute__((ext_vector_type(8)));

__device__ __forceinline__ float fexp2(float x){ return __builtin_amdgcn_exp2f(x); }
__device__ __forceinline__ float flog2(float x){ return __builtin_amdgcn_logf(x); }

// sqrt(1/(2*ln2)): exp2(-((t*CS)^2)) = exp(-t^2/2)
#define CS 0.8493218002880191f

// ws float layout
#define OFF_PART   0            // 32*256 partial col sums
#define OFF_ACCUM  8192         // 256 final col sums
#define OFF_JOINT  8448         // 2048
#define OFF_SLOG   10496        // 2048
#define OFF_MOM    12544        // 16*128*10 = 20480
#define OFF_CTR    33024        // 1 uint (pad 4)
#define OFF_XS     33028        // ushort[2048*128] = 65536 float slots; byte off 132112 (16B aligned)
#define ZERO_BASE  OFF_JOINT
#define ZERO_LEN   (2048 + 2048 + 20480 + 4)

__device__ __forceinline__ void col_stats_from(float s, float s2, float& scale, float& shift){
  float m = s * (1.f / NROWS);
  float var = fmaxf((s2 - (float)NROWS * m * m) * (1.f / (NROWS - 1)), 0.f);
  scale = 1.f / (sqrtf(var) + 1e-6f);
  shift = -m * scale;
}

// ---------------- K1: partial col sums + zero accumulators -------------------
__global__ __launch_bounds__(1024) void tc_stats(const float* __restrict__ x,
                                                 float* __restrict__ ws){
  const int t  = threadIdx.x;
  const int k  = t & 127;
  const int rg = t >> 7;
  const int r0 = blockIdx.x * 64;
  {
    int idx = blockIdx.x * 1024 + t;
    if (idx < ZERO_LEN) ws[ZERO_BASE + idx] = 0.f;
  }
  float s = 0.f, s2 = 0.f;
  #pragma unroll
  for (int it = 0; it < 8; ++it){
    float v = x[(size_t)(r0 + it * 8 + rg) * KDIM + k];
    s += v;
    s2 = fmaf(v, v, s2);
  }
  __shared__ float ls[8][128], ls2[8][128];
  ls[rg][k] = s; ls2[rg][k] = s2;
  __syncthreads();
  if (t < 128){
    float a = 0.f, b = 0.f;
    #pragma unroll
    for (int g = 0; g < 8; ++g){ a += ls[g][t]; b += ls2[g][t]; }
    ws[OFF_PART + blockIdx.x * 256 + t]       = a;
    ws[OFF_PART + blockIdx.x * 256 + 128 + t] = b;
  }
}

// ---------------- K2: FGT moments + bf16 pack + accum write ------------------
// grid 2048 = 128 k x 16 row-segs; 128 threads.
__global__ __launch_bounds__(128) void tc_moments(const float* __restrict__ x,
                                                  float* __restrict__ ws){
  const int k   = blockIdx.x >> 4;
  const int seg = blockIdx.x & 15;
  const int t   = threadIdx.x;
  __shared__ float lm[NCELL * PORD];   // 160
  lm[t] = 0.f;
  if (t < 32) lm[128 + t] = 0.f;

  float s = 0.f, s2 = 0.f;
  #pragma unroll
  for (int b = 0; b < 32; ++b){
    s  += ws[OFF_PART + b * 256 + k];
    s2 += ws[OFF_PART + b * 256 + 128 + k];
  }
  if (seg == 0 && t == 0){
    ws[OFF_ACCUM + k]       = s;
    ws[OFF_ACCUM + 128 + k] = s2;
  }
  float scale, shift; col_stats_from(s, s2, scale, shift);
  __syncthreads();

  const int row = seg * 128 + t;
  float y = fmaf(x[(size_t)row * KDIM + k], scale, shift);

  // CS-folded bf16 pack for the MFMA kernel
  {
    __hip_bfloat16 hb = __float2bfloat16(y * CS);
    ((unsigned short*)(ws + OFF_XS))[(size_t)row * KDIM + k] = *(unsigned short*)&hb;
  }

  int c = (int)floorf(y * 2.f + 8.f);
  c = min(max(c, 0), NCELL - 1);
  float u = y - (-3.75f + 0.5f * (float)c);
  float* b10 = &lm[c * PORD];
  atomicAdd(&b10[0], 1.f);
  float pw = u;
  atomicAdd(&b10[1], pw);
  pw *= u; atomicAdd(&b10[2], pw * 0.5f);
  pw *= u; atomicAdd(&b10[3], pw * 1.6666666666e-1f);
  pw *= u; atomicAdd(&b10[4], pw * 4.1666666666e-2f);
  pw *= u; atomicAdd(&b10[5], pw * 8.3333333333e-3f);
  pw *= u; atomicAdd(&b10[6], pw * 1.3888888889e-3f);
  pw *= u; atomicAdd(&b10[7], pw * 1.9841269841e-4f);
  pw *= u; atomicAdd(&b10[8], pw * 2.4801587302e-5f);
  pw *= u; atomicAdd(&b10[9], pw * 2.7557319224e-6f);
  __syncthreads();

  float* mom = ws + OFF_MOM;
  for (int idx = t; idx < NCELL * PORD; idx += 128){
    int c2 = idx / PORD, m = idx - c2 * PORD;
    atomicAdd(&mom[(size_t)(c2 * KDIM + k) * PORD + m], lm[idx]);
  }
}

// ---------------- K3: MFMA Gram joint + FGT eval + finalize ------------------
// 512 blocks x 512 thr; block = (bi,bj) -> G-tile rows [bi*128,+128) x cols [bj*64,+64)
__global__ __launch_bounds__(512) void tc_joint(const float* __restrict__ x,
                                                float* __restrict__ ws,
                                                float* __restrict__ out){
  __shared__ __align__(16) char ls[49152];      // A 32KB + B 16KB, XOR-swizzled
  __shared__ float nI[128], nJ[64];
  __shared__ float red2[8];
  __shared__ int lastflag;

  const int t = threadIdx.x;
  const int wave = t >> 6, lane = t & 63;
  const int bid = blockIdx.x;
  const int bi = bid >> 5, bj = bid & 31;
  const int Ibase = bi * 128, Jbase = bj * 64;
  float* joint = ws + OFF_JOINT;
  float* slog  = ws + OFF_SLOG;
  const float* accum = ws + OFF_ACCUM;
  const float* mom   = ws + OFF_MOM;
  const unsigned short* xs = (const unsigned short*)(ws + OFF_XS);

  // stage A (128 rows x 256B) and B (64 rows x 256B), swizzle byte^=(row&7)<<4
  #pragma unroll
  for (int q = 0; q < 4; ++q){
    int g = t + q * 512;                 // 0..2047 granules of 16B
    int row = g >> 4, c16 = g & 15;
    uint4 v = *(const uint4*)(xs + (size_t)(Ibase + row) * KDIM + c16 * 8);
    *(uint4*)(ls + row * 256 + ((c16 * 16) ^ ((row & 7) << 4))) = v;
  }
  #pragma unroll
  for (int q = 0; q < 2; ++q){
    int g = t + q * 512;                 // 0..1023
    int row = g >> 4, c16 = g & 15;
    uint4 v = *(const uint4*)(xs + (size_t)(Jbase + row) * KDIM + c16 * 8);
    *(uint4*)(ls + 32768 + row * 256 + ((c16 * 16) ^ ((row & 7) << 4))) = v;
  }
  __syncthreads();

  // norms from staged bf16 (consistent with MFMA inputs)
  if (t < 192){
    int row = (t < 128) ? t : (t - 128);
    const char* base = (t < 128) ? ls : (ls + 32768);
    float n = 0.f;
    #pragma unroll
    for (int g2 = 0; g2 < 16; ++g2){
      uint4 v = *(const uint4*)(base + row * 256 + ((g2 * 16) ^ ((row & 7) << 4)));
      const unsigned int* u = (const unsigned int*)&v;
      #pragma unroll
      for (int e = 0; e < 4; ++e){
        float lo = __builtin_bit_cast(float, u[e] << 16);
        float hi = __builtin_bit_cast(float, u[e] & 0xFFFF0000u);
        n = fmaf(lo, lo, n); n = fmaf(hi, hi, n);
      }
    }
    if (t < 128) nI[row] = n; else nJ[row] = n;
  }
  __syncthreads();

  // MFMA: wave (wi=wave>>2, wj=wave&3) -> 64i x 16j region, 4 m-tiles
  const int wi = wave >> 2, wj = wave & 3;
  const int mrow0 = wi * 64 + (lane & 15);
  const int nrow  = wj * 16 + (lane & 15);
  f32x4 acc0 = {0.f,0.f,0.f,0.f}, acc1 = acc0, acc2 = acc0, acc3 = acc0;
  #pragma unroll
  for (int kq = 0; kq < 4; ++kq){
    const int boff = kq * 64 + (lane >> 4) * 16;
    const int mx = (mrow0 & 7) << 4;
    bf16x8 bf = *(const bf16x8*)(ls + 32768 + nrow * 256 + (boff ^ ((nrow & 7) << 4)));
    bf16x8 a0 = *(const bf16x8*)(ls + (mrow0 +  0) * 256 + (boff ^ mx));
    bf16x8 a1 = *(const bf16x8*)(ls + (mrow0 + 16) * 256 + (boff ^ mx));
    bf16x8 a2 = *(const bf16x8*)(ls + (mrow0 + 32) * 256 + (boff ^ mx));
    bf16x8 a3 = *(const bf16x8*)(ls + (mrow0 + 48) * 256 + (boff ^ mx));
    acc0 = __builtin_amdgcn_mfma_f32_16x16x32_bf16(a0, bf, acc0, 0, 0, 0);
    acc1 = __builtin_amdgcn_mfma_f32_16x16x32_bf16(a1, bf, acc1, 0, 0, 0);
    acc2 = __builtin_amdgcn_mfma_f32_16x16x32_bf16(a2, bf, acc2, 0, 0, 0);
    acc3 = __builtin_amdgcn_mfma_f32_16x16x32_bf16(a3, bf, acc3, 0, 0, 0);
  }

  // epilogue: pd = nI + nJ - 2g; exp2(-pd) flushes to 0 for far pairs; row-reduce
  const float njv = nJ[nrow];
  const int rbase = (lane >> 4) * 4;
  float jp[4][4];
  #pragma unroll
  for (int mt = 0; mt < 4; ++mt){
    f32x4 a4 = (mt == 0) ? acc0 : (mt == 1) ? acc1 : (mt == 2) ? acc2 : acc3;
    #pragma unroll
    for (int p = 0; p < 4; ++p){
      int iloc = wi * 64 + mt * 16 + rbase + p;
      float pd = nI[iloc] + njv - 2.f * a4[p];
      jp[mt][p] = fexp2(-pd);
    }
  }
  #pragma unroll
  for (int mt = 0; mt < 4; ++mt){
    #pragma unroll
    for (int p = 0; p < 4; ++p){
      float v = jp[mt][p];
      v += __shfl_xor(v, 1); v += __shfl_xor(v, 2);
      v += __shfl_xor(v, 4); v += __shfl_xor(v, 8);
      jp[mt][p] = v;
    }
  }
  if ((lane & 15) == 0){
    #pragma unroll
    for (int mt = 0; mt < 4; ++mt)
      #pragma unroll
      for (int p = 0; p < 4; ++p)
        atomicAdd(&joint[Ibase + wi * 64 + mt * 16 + rbase + p], jp[mt][p]);
  }

  // ---- FGT eval side-job: rows bid*4..+3, 128 k each ----
  {
    const int k  = t & 127;
    const int ir = t >> 7;
    const int r  = bid * 4 + ir;
    float scale, shift;
    col_stats_from(accum[k], accum[128 + k], scale, shift);
    const float y = fmaf(x[(size_t)r * KDIM + k], scale, shift);
    float S = 0.f;
    #pragma unroll
    for (int c = 0; c < NCELL; ++c){
      const float* mp = mom + (size_t)(c * KDIM + k) * PORD;
      float q0 = mp[0], q1 = mp[1], q2 = mp[2], q3 = mp[3], q4 = mp[4];
      float q5 = mp[5], q6 = mp[6], q7 = mp[7], q8 = mp[8], q9 = mp[9];
      float sC  = y - (-3.75f + 0.5f * (float)c);
      float scl = sC * CS;
      float e  = fexp2(-(scl * scl));
      float prev = 1.f, cur = sC, nxt;
      float inner = fmaf(q1, sC, q0);
      nxt = fmaf(sC, cur, -1.f * prev); inner = fmaf(q2, nxt, inner); prev = cur; cur = nxt;
      nxt = fmaf(sC, cur, -2.f * prev); inner = fmaf(q3, nxt, inner); prev = cur; cur = nxt;
      nxt = fmaf(sC, cur, -3.f * prev); inner = fmaf(q4, nxt, inner); prev = cur; cur = nxt;
      nxt = fmaf(sC, cur, -4.f * prev); inner = fmaf(q5, nxt, inner); prev = cur; cur = nxt;
      nxt = fmaf(sC, cur, -5.f * prev); inner = fmaf(q6, nxt, inner); prev = cur; cur = nxt;
      nxt = fmaf(sC, cur, -6.f * prev); inner = fmaf(q7, nxt, inner); prev = cur; cur = nxt;
      nxt = fmaf(sC, cur, -7.f * prev); inner = fmaf(q8, nxt, inner); prev = cur; cur = nxt;
      nxt = fmaf(sC, cur, -8.f * prev); inner = fmaf(q9, nxt, inner);
      S = fmaf(e, inner, S);
    }
    float lg = flog2(S);
    #pragma unroll
    for (int off = 1; off < 64; off <<= 1) lg += __shfl_xor(lg, off);
    if (lane == 0) atomicAdd(&slog[r], lg);
  }

  // ---- arrival counter; last block finalizes ----
  __syncthreads();
  if (t == 0){
    __threadfence();
    unsigned int* ctr = (unsigned int*)(ws + OFF_CTR);
    unsigned int old = __hip_atomic_fetch_add(ctr, 1u, __ATOMIC_ACQ_REL, __HIP_MEMORY_SCOPE_AGENT);
    lastflag = (old == NJBLK - 1);
  }
  __syncthreads();
  if (lastflag){
    float acc = 0.f;
    #pragma unroll
    for (int q = 0; q < 4; ++q){
      int r = q * 512 + t;
      float jv = __hip_atomic_load(&joint[r], __ATOMIC_RELAXED, __HIP_MEMORY_SCOPE_AGENT);
      float sv = __hip_atomic_load(&slog[r],  __ATOMIC_RELAXED, __HIP_MEMORY_SCOPE_AGENT);
      acc += 0.6931471805599453f * (flog2(jv) - sv);
    }
    #pragma unroll
    for (int m = 1; m < 64; m <<= 1) acc += __shfl_xor(acc, m);
    if (lane == 0) red2[wave] = acc;
    __syncthreads();
    if (t == 0){
      float tot = 0.f;
      #pragma unroll
      for (int w = 0; w < 8; ++w) tot += red2[w];
      out[0] = tot * (1.0f / NROWS) + 968.32661124224364f;  // +127*ln(2048)
    }
  }
}

// ---------------- launch -----------------------------------------------------
extern "C" void kernel_launch(void* const* d_in, const int* in_sizes, int n_in,
                              void* d_out, int out_size, void* d_ws, size_t ws_size,
                              hipStream_t stream){
  const float* x = (const float*)d_in[0];
  float* out = (float*)d_out;
  float* ws  = (float*)d_ws;
  tc_stats  <<<32, 1024, 0, stream>>>(x, ws);
  tc_moments<<<KDIM * 16, 128, 0, stream>>>(x, ws);
  tc_joint  <<<NJBLK, 512, 0, stream>>>(x, ws, out);
}